// Round 3
// baseline (188.523 us; speedup 1.0000x reference)
//
#include <hip/hip_runtime.h>

#define NHEADS 8
#define HD 16
#define DMODEL 128
#define SLEN 1024
#define BATCH 4
#define MAXL 500

#define QT 16      // q rows per block (attention)
#define KT 64      // k cols per tile
#define BAND 80    // 79 rows of E band, padded
#define PAD 20     // LDS row stride in floats (16 data + 4 pad, 16B-aligned rows)

// ---------------- Q/K/V projection: dst[b,h,s,d] = (x @ W^T + b)[,h*16+d] * scale ----
__global__ __launch_bounds__(256) void qkv_proj_kernel(
    const float* __restrict__ q_in, const float* __restrict__ k_in, const float* __restrict__ v_in,
    const float* __restrict__ Wq, const float* __restrict__ bq,
    const float* __restrict__ Wk, const float* __restrict__ bk,
    const float* __restrict__ Wv, const float* __restrict__ bv,
    float* __restrict__ Qh, float* __restrict__ Kh, float* __restrict__ Vh)
{
    const int which = blockIdx.y;
    const float* x  = (which == 0) ? q_in : (which == 1) ? k_in : v_in;
    const float* W  = (which == 0) ? Wq   : (which == 1) ? Wk   : Wv;
    const float* bb = (which == 0) ? bq   : (which == 1) ? bk   : bv;
    float* dst      = (which == 0) ? Qh   : (which == 1) ? Kh   : Vh;
    const float scale = (which == 1) ? 0.25f : 1.0f;   // fold 1/sqrt(hd) into K

    __shared__ float Xs[32][129];
    __shared__ float Wt[64][129];   // Wt[k][c] = W[c][k], staged in two k-halves

    const int t = threadIdx.x;
    const int row0 = blockIdx.x * 32;

    for (int e = t; e < 32 * 128; e += 256) {
        int r = e >> 7, k = e & 127;
        Xs[r][k] = x[(size_t)(row0 + r) * 128 + k];
    }

    const int tr = t >> 5;   // 0..7  -> rows tr*4 .. tr*4+3
    const int tc = t & 31;   // cols tc + 32*j
    float acc[4][4];
    #pragma unroll
    for (int i = 0; i < 4; ++i)
        #pragma unroll
        for (int j = 0; j < 4; ++j) acc[i][j] = bb[tc + 32 * j];

    for (int p = 0; p < 2; ++p) {
        __syncthreads();
        for (int e = t; e < 64 * 128; e += 256) {
            int c = e >> 6, kk = e & 63;
            Wt[kk][c] = W[c * 128 + p * 64 + kk];
        }
        __syncthreads();
        for (int kk = 0; kk < 64; ++kk) {
            float xr[4], wc[4];
            int k = p * 64 + kk;
            #pragma unroll
            for (int i = 0; i < 4; ++i) xr[i] = Xs[tr * 4 + i][k];
            #pragma unroll
            for (int j = 0; j < 4; ++j) wc[j] = Wt[kk][tc + 32 * j];
            #pragma unroll
            for (int i = 0; i < 4; ++i)
                #pragma unroll
                for (int j = 0; j < 4; ++j) acc[i][j] += xr[i] * wc[j];
        }
    }

    #pragma unroll
    for (int i = 0; i < 4; ++i) {
        int row = row0 + tr * 4 + i;
        int b = row >> 10, s = row & 1023;
        #pragma unroll
        for (int j = 0; j < 4; ++j) {
            int c = tc + 32 * j;
            int h = c >> 4, d = c & 15;
            dst[((size_t)(b * NHEADS + h) * SLEN + s) * HD + d] = acc[i][j] * scale;
        }
    }
}

// ---------------- flash attention with relative-position band ----------------
// block: 256 threads = (qi 0..15) x (g 0..15); one (b,h) + 16 q-rows per block.
// logit(q,k) = Q[q] . (0.25*K[k] + emb[clip(k-q)+500][h*16:...])
__global__ __launch_bounds__(256) void attn_kernel(
    const float* __restrict__ Qh, const float* __restrict__ Kh, const float* __restrict__ Vh,
    const float* __restrict__ emb, float* __restrict__ Oh)
{
    const int bh = blockIdx.y;
    const int h  = bh & (NHEADS - 1);
    const int q0 = blockIdx.x * QT;
    const int t  = threadIdx.x;
    const int qi = t >> 4;   // q row within tile
    const int g  = t & 15;   // k group (split-k lane)

    __shared__ __align__(16) float Qs[QT][PAD];
    __shared__ __align__(16) float Ks[KT][PAD];
    __shared__ __align__(16) float Vs[KT][PAD];
    __shared__ __align__(16) float Es[BAND][PAD];
    __shared__ float Mb[QT][16];
    __shared__ float Lb[QT][16];
    __shared__ __align__(16) float Ob[QT][16][PAD];

    const float* Qbase = Qh + (size_t)bh * SLEN * HD;
    const float* Kbase = Kh + (size_t)bh * SLEN * HD;
    const float* Vbase = Vh + (size_t)bh * SLEN * HD;

    Qs[t >> 4][t & 15] = Qbase[(size_t)(q0 + (t >> 4)) * HD + (t & 15)];
    __syncthreads();
    float qreg[HD];
    #pragma unroll
    for (int d = 0; d < HD; ++d) qreg[d] = Qs[qi][d];

    float m = -1e30f, l = 0.f;
    float o[HD];
    #pragma unroll
    for (int d = 0; d < HD; ++d) o[d] = 0.f;

    for (int k0 = 0; k0 < SLEN; k0 += KT) {
        __syncthreads();
        // stage K', V tiles (64 x 16)
        #pragma unroll
        for (int p = 0; p < 4; ++p) {
            int r = (t >> 4) + p * 16;
            int d = t & 15;
            Ks[r][d] = Kbase[(size_t)(k0 + r) * HD + d];
            Vs[r][d] = Vbase[(size_t)(k0 + r) * HD + d];
        }
        // stage E band: row r corresponds to rel = k0-q0-15+r (clamped to +-500)
        #pragma unroll
        for (int p = 0; p < 5; ++p) {
            int r = (t >> 4) + p * 16;
            if (r < QT + KT - 1) {
                int rel = k0 - q0 - (QT - 1) + r;
                rel = rel < -MAXL ? -MAXL : (rel > MAXL ? MAXL : rel);
                Es[r][t & 15] = emb[(size_t)(rel + MAXL) * DMODEL + h * HD + (t & 15)];
            }
        }
        __syncthreads();

        float lg[4];
        #pragma unroll
        for (int j = 0; j < 4; ++j) {
            int kl = g + 16 * j;
            int er = kl - qi + (QT - 1);   // 0..78
            const float4* k4 = (const float4*)(&Ks[kl][0]);
            const float4* e4 = (const float4*)(&Es[er][0]);
            float accv = 0.f;
            #pragma unroll
            for (int c = 0; c < 4; ++c) {
                float4 kv = k4[c], ev = e4[c];
                accv += qreg[4 * c + 0] * (kv.x + ev.x);
                accv += qreg[4 * c + 1] * (kv.y + ev.y);
                accv += qreg[4 * c + 2] * (kv.z + ev.z);
                accv += qreg[4 * c + 3] * (kv.w + ev.w);
            }
            lg[j] = accv;
        }
        float tm = fmaxf(fmaxf(lg[0], lg[1]), fmaxf(lg[2], lg[3]));
        float mn = fmaxf(m, tm);
        float sc = __expf(m - mn);
        float p0 = __expf(lg[0] - mn);
        float p1 = __expf(lg[1] - mn);
        float p2 = __expf(lg[2] - mn);
        float p3 = __expf(lg[3] - mn);
        l = l * sc + (p0 + p1 + p2 + p3);
        m = mn;
        const float4* v0 = (const float4*)(&Vs[g][0]);
        const float4* v1 = (const float4*)(&Vs[g + 16][0]);
        const float4* v2 = (const float4*)(&Vs[g + 32][0]);
        const float4* v3 = (const float4*)(&Vs[g + 48][0]);
        #pragma unroll
        for (int c = 0; c < 4; ++c) {
            float4 a = v0[c], bv = v1[c], cv = v2[c], dv = v3[c];
            o[4 * c + 0] = o[4 * c + 0] * sc + p0 * a.x + p1 * bv.x + p2 * cv.x + p3 * dv.x;
            o[4 * c + 1] = o[4 * c + 1] * sc + p0 * a.y + p1 * bv.y + p2 * cv.y + p3 * dv.y;
            o[4 * c + 2] = o[4 * c + 2] * sc + p0 * a.z + p1 * bv.z + p2 * cv.z + p3 * dv.z;
            o[4 * c + 3] = o[4 * c + 3] * sc + p0 * a.w + p1 * bv.w + p2 * cv.w + p3 * dv.w;
        }
    }

    // merge the 16 split-k partials per q row
    Mb[qi][g] = m;
    Lb[qi][g] = l;
    #pragma unroll
    for (int d = 0; d < HD; ++d) Ob[qi][g][d] = o[d];
    __syncthreads();

    {
        int d = g;
        float M = -1e30f;
        #pragma unroll
        for (int i = 0; i < 16; ++i) M = fmaxf(M, Mb[qi][i]);
        float L = 0.f, acc = 0.f;
        #pragma unroll
        for (int i = 0; i < 16; ++i) {
            float w = __expf(Mb[qi][i] - M);
            L += Lb[qi][i] * w;
            acc += Ob[qi][i][d] * w;
        }
        Oh[((size_t)bh * SLEN + q0 + qi) * HD + d] = acc / L;
    }
}

// ---------------- output projection: out = concat_h(O) @ Wo^T + bo ----------------
__global__ __launch_bounds__(256) void out_proj_kernel(
    const float* __restrict__ Oh, const float* __restrict__ Wo, const float* __restrict__ bo,
    float* __restrict__ out)
{
    __shared__ float Xs[32][129];
    __shared__ float Wt[64][129];

    const int t = threadIdx.x;
    const int row0 = blockIdx.x * 32;

    for (int e = t; e < 32 * 128; e += 256) {
        int r = e >> 7, i = e & 127;
        int row = row0 + r;
        int b = row >> 10, s = row & 1023;
        Xs[r][i] = Oh[((size_t)(b * NHEADS + (i >> 4)) * SLEN + s) * HD + (i & 15)];
    }

    const int tr = t >> 5;
    const int tc = t & 31;
    float acc[4][4];
    #pragma unroll
    for (int i = 0; i < 4; ++i)
        #pragma unroll
        for (int j = 0; j < 4; ++j) acc[i][j] = bo[tc + 32 * j];

    for (int p = 0; p < 2; ++p) {
        __syncthreads();
        for (int e = t; e < 64 * 128; e += 256) {
            int c = e >> 6, kk = e & 63;
            Wt[kk][c] = Wo[c * 128 + p * 64 + kk];
        }
        __syncthreads();
        for (int kk = 0; kk < 64; ++kk) {
            float xr[4], wc[4];
            int k = p * 64 + kk;
            #pragma unroll
            for (int i = 0; i < 4; ++i) xr[i] = Xs[tr * 4 + i][k];
            #pragma unroll
            for (int j = 0; j < 4; ++j) wc[j] = Wt[kk][tc + 32 * j];
            #pragma unroll
            for (int i = 0; i < 4; ++i)
                #pragma unroll
                for (int j = 0; j < 4; ++j) acc[i][j] += xr[i] * wc[j];
        }
    }

    // round-trip through LDS for fully coalesced stores
    __syncthreads();
    #pragma unroll
    for (int i = 0; i < 4; ++i)
        #pragma unroll
        for (int j = 0; j < 4; ++j) Xs[tr * 4 + i][tc + 32 * j] = acc[i][j];
    __syncthreads();
    for (int e = t; e < 32 * 128; e += 256)
        out[(size_t)row0 * 128 + e] = Xs[e >> 7][e & 127];
}

extern "C" void kernel_launch(void* const* d_in, const int* in_sizes, int n_in,
                              void* d_out, int out_size, void* d_ws, size_t ws_size,
                              hipStream_t stream)
{
    const float* query  = (const float*)d_in[0];
    const float* key_in = (const float*)d_in[1];
    const float* value  = (const float*)d_in[2];
    const float* Wq = (const float*)d_in[3];
    const float* bq = (const float*)d_in[4];
    const float* Wk = (const float*)d_in[5];
    const float* bk = (const float*)d_in[6];
    const float* Wv = (const float*)d_in[7];
    const float* bv = (const float*)d_in[8];
    const float* Wo = (const float*)d_in[9];
    const float* bo = (const float*)d_in[10];
    const float* emb = (const float*)d_in[11];
    float* out = (float*)d_out;

    // workspace: 4 tensors of [B,H,S,16] f32 = 8 MB total
    float* ws = (float*)d_ws;
    const size_t TEN = (size_t)BATCH * NHEADS * SLEN * HD;  // 524288
    float* Qh = ws;
    float* Kh = ws + TEN;
    float* Vh = ws + 2 * TEN;
    float* Oh = ws + 3 * TEN;

    qkv_proj_kernel<<<dim3(4096 / 32, 3), 256, 0, stream>>>(
        query, key_in, value, Wq, bq, Wk, bk, Wv, bv, Qh, Kh, Vh);
    attn_kernel<<<dim3(SLEN / QT, BATCH * NHEADS), 256, 0, stream>>>(
        Qh, Kh, Vh, emb, Oh);
    out_proj_kernel<<<dim3(4096 / 32), 256, 0, stream>>>(Oh, Wo, bo, out);
}

// Round 5
// 155.298 us; speedup vs baseline: 1.2139x; 1.2139x over previous
//
#include <hip/hip_runtime.h>

#define NH 8
#define HD 16
#define SLEN 1024
#define BATCH 4
#define MAXL 500

typedef float f32x4  __attribute__((ext_vector_type(4)));
typedef float f32x16 __attribute__((ext_vector_type(16)));
typedef short s16x8  __attribute__((ext_vector_type(8)));

__device__ inline ushort f2bf(float f) {
    uint u = __builtin_bit_cast(uint, f);
    u = (u + 0x7fffu + ((u >> 16) & 1u)) >> 16;
    return (ushort)u;
}
__device__ inline float bf2f(ushort h) {
    uint u = ((uint)h) << 16;
    return __builtin_bit_cast(float, u);
}

// ================= QKV projection (bf16 MFMA GEMM) =================
// out[m][n] = sum_k x[m][k] * W[n][k] + b[n];  m in [0,4096), n in [0,128)
// mode 0: Q -> Qh[bh][s][d] bf16
// mode 1: K -> Kh[bh][s][d] bf16, scaled by 0.25 (1/sqrt(hd))
// mode 2: V -> Vt[bh][d][s] bf16 (transposed for PV B-operand)
__global__ __launch_bounds__(256) void qkv_proj_mfma(
    const float* __restrict__ xq, const float* __restrict__ xk, const float* __restrict__ xv,
    const float* __restrict__ Wq, const float* __restrict__ bq,
    const float* __restrict__ Wk, const float* __restrict__ bk,
    const float* __restrict__ Wv, const float* __restrict__ bv,
    ushort* __restrict__ Qh, ushort* __restrict__ Kh, ushort* __restrict__ Vt)
{
    const int mode = blockIdx.y;
    const float* x  = (mode == 0) ? xq : (mode == 1) ? xk : xv;
    const float* W  = (mode == 0) ? Wq : (mode == 1) ? Wk : Wv;
    const float* bb = (mode == 0) ? bq : (mode == 1) ? bk : bv;

    __shared__ __align__(16) ushort Xs[64][40];
    __shared__ __align__(16) ushort Ws[128][40];

    const int t = threadIdx.x;
    const int wid = t >> 6, lane = t & 63;
    const int m0 = blockIdx.x * 64;

    f32x4 acc[4][2];
    #pragma unroll
    for (int i = 0; i < 4; ++i)
        #pragma unroll
        for (int j = 0; j < 2; ++j)
            #pragma unroll
            for (int r = 0; r < 4; ++r) acc[i][j][r] = 0.f;

    for (int k0 = 0; k0 < 128; k0 += 32) {
        __syncthreads();
        {   // stage X tile [64][32] -> bf16
            int m = t >> 2, kb = (t & 3) * 8;
            const float* src = &x[(size_t)(m0 + m) * 128 + k0 + kb];
            const float4 a = *(const float4*)src;
            const float4 b4 = *(const float4*)(src + 4);
            ushort tmp[8] = {f2bf(a.x),f2bf(a.y),f2bf(a.z),f2bf(a.w),
                             f2bf(b4.x),f2bf(b4.y),f2bf(b4.z),f2bf(b4.w)};
            *(s16x8*)&Xs[m][kb] = *(const s16x8*)tmp;
        }
        {   // stage W tile [128][32] -> bf16
            int n = t >> 1, kb = (t & 1) * 16;
            const float* src = &W[(size_t)n * 128 + k0 + kb];
            ushort tmp[16];
            #pragma unroll
            for (int i = 0; i < 16; ++i) tmp[i] = f2bf(src[i]);
            *(s16x8*)&Ws[n][kb]     = *(const s16x8*)&tmp[0];
            *(s16x8*)&Ws[n][kb + 8] = *(const s16x8*)&tmp[8];
        }
        __syncthreads();
        s16x8 af[4], bf[2];
        #pragma unroll
        for (int ms = 0; ms < 4; ++ms)
            af[ms] = *(const s16x8*)&Xs[16*ms + (lane & 15)][8 * (lane >> 4)];
        #pragma unroll
        for (int ns = 0; ns < 2; ++ns)
            bf[ns] = *(const s16x8*)&Ws[32*wid + 16*ns + (lane & 15)][8 * (lane >> 4)];
        #pragma unroll
        for (int ms = 0; ms < 4; ++ms)
            #pragma unroll
            for (int ns = 0; ns < 2; ++ns)
                acc[ms][ns] = __builtin_amdgcn_mfma_f32_16x16x32_bf16(af[ms], bf[ns], acc[ms][ns], 0, 0, 0);
    }

    const float scale = (mode == 1) ? 0.25f : 1.0f;
    const int b = m0 >> 10;            // batch (constant per block: 64 | 1024)
    #pragma unroll
    for (int ns = 0; ns < 2; ++ns) {
        const int n = 32*wid + 16*ns + (lane & 15);
        const int hh = n >> 4, d = n & 15;
        const float bias = bb[n];
        #pragma unroll
        for (int ms = 0; ms < 4; ++ms) {
            if (mode == 2) {
                // V transposed: Vt[(b*8+hh)*16+d][s], 4 consecutive s per reg-quad
                ushort4 pk;
                pk.x = f2bf(acc[ms][ns][0] + bias);
                pk.y = f2bf(acc[ms][ns][1] + bias);
                pk.z = f2bf(acc[ms][ns][2] + bias);
                pk.w = f2bf(acc[ms][ns][3] + bias);
                int s0 = (m0 & 1023) + 16*ms + (lane >> 4) * 4;
                *(ushort4*)&Vt[((size_t)((b*8 + hh)*16 + d)) * SLEN + s0] = pk;
            } else {
                ushort* dst = (mode == 0) ? Qh : Kh;
                #pragma unroll
                for (int r = 0; r < 4; ++r) {
                    int mm = m0 + 16*ms + (lane >> 4) * 4 + r;
                    int s = mm & 1023;
                    float v = (acc[ms][ns][r] + bias) * scale;
                    dst[((size_t)(b*8 + hh) * SLEN + s) * HD + d] = f2bf(v);
                }
            }
        }
    }
}

// ================= fused flash attention with relative-position bias (MFMA) ======
// grid (8 qgroups, 32 bh); 256 thr = 4 waves; wave = 32 q rows; k-tiles of 32.
__global__ __launch_bounds__(256) void attn_mfma(
    const ushort* __restrict__ Qh, const ushort* __restrict__ Kh,
    const ushort* __restrict__ Vtg, const float* __restrict__ emb,
    float* __restrict__ Oh2)
{
    __shared__ __align__(16) ushort Qs[128][24];
    __shared__ __align__(16) ushort Kt[32][24];
    __shared__ __align__(16) ushort Vt[16][40];
    __shared__ __align__(16) ushort Eb[160][24];
    __shared__ __align__(16) ushort Pl[4][32][40];
    __shared__ __align__(16) ushort Rl[4][64][36];
    __shared__ float scb[4][32];
    __shared__ float lb[4][32];

    const int tid = threadIdx.x;
    const int wid = tid >> 6, lane = tid & 63;
    const int hi = lane >> 5, q = lane & 31;
    const int bh = blockIdx.y, h = bh & 7;
    const int q0b = blockIdx.x * 128;
    const int q0w = q0b + wid * 32;

    {   // stage Q rows (128 x 16 bf16)
        int row = tid >> 1, hf = tid & 1;
        const ushort* src = &Qh[((size_t)bh * SLEN + q0b + row) * HD + hf * 8];
        *(s16x8*)&Qs[row][hf * 8] = *(const s16x8*)src;
    }
    __syncthreads();
    const s16x8 qf = *(const s16x8*)&Qs[wid * 32 + q][8 * hi];

    f32x4 o0, o1;
    #pragma unroll
    for (int r = 0; r < 4; ++r) { o0[r] = 0.f; o1[r] = 0.f; }
    float m = -1e30f, l = 0.f;

    for (int kt = 0; kt < 32; ++kt) {
        const int k0 = kt * 32;
        __syncthreads();
        {   // stage K tile [32][16]
            int e = tid * 2, r = e >> 4, d0 = e & 15;
            *(ushort2*)&Kt[r][d0] = *(const ushort2*)&Kh[((size_t)bh * SLEN + k0 + r) * HD + d0];
        }
        {   // stage V^T tile [16 d][32 k]
            int d = tid >> 4, kk = (tid & 15) * 2;
            *(ushort2*)&Vt[d][kk] = *(const ushort2*)&Vtg[((size_t)(bh * 16 + d)) * SLEN + k0 + kk];
        }
        {   // stage emb band [160 rel][16 kd]
            const int relbase = k0 - q0b - 127;
            for (int e = tid; e < 160 * 4; e += 256) {
                int r = e >> 2, c4 = (e & 3) * 4;
                int rel = relbase + r;
                rel = rel < -MAXL ? -MAXL : (rel > MAXL ? MAXL : rel);
                const float4 v = *(const float4*)&emb[(size_t)(rel + MAXL) * 128 + h * HD + c4];
                ushort4 pk; pk.x = f2bf(v.x); pk.y = f2bf(v.y); pk.z = f2bf(v.z); pk.w = f2bf(v.w);
                *(ushort4*)&Eb[r][c4] = pk;
            }
        }
        __syncthreads();

        // --- QK^T (swapped): sa = S^T[krow][q], krow = (r&3)+8*(r>>2)+4*hi ---
        const s16x8 kf = *(const s16x8*)&Kt[q][8 * hi];
        f32x16 sa;
        #pragma unroll
        for (int i = 0; i < 16; ++i) sa[i] = 0.f;
        sa = __builtin_amdgcn_mfma_f32_32x32x16_bf16(kf, qf, sa, 0, 0, 0);

        // --- R GEMM: R[q][n] = Q[q] . emb(relbase + j0w + n), n in [0,64) ---
        const int j0w = 96 - 32 * wid;
        #pragma unroll
        for (int st = 0; st < 2; ++st) {
            const s16x8 ef = *(const s16x8*)&Eb[j0w + 32 * st + q][8 * hi];
            f32x16 ra;
            #pragma unroll
            for (int i = 0; i < 16; ++i) ra[i] = 0.f;
            ra = __builtin_amdgcn_mfma_f32_32x32x16_bf16(qf, ef, ra, 0, 0, 0);
            // lane holds col n=32*st+q, rows q' in quads: write Rl[n][q'] bf16
            #pragma unroll
            for (int g = 0; g < 4; ++g) {
                ushort4 pk;
                pk.x = f2bf(ra[4*g + 0]); pk.y = f2bf(ra[4*g + 1]);
                pk.z = f2bf(ra[4*g + 2]); pk.w = f2bf(ra[4*g + 3]);
                *(ushort4*)&Rl[wid][32*st + q][8*g + 4*hi] = pk;
            }
        }

        // --- bias gather + online softmax (lane owns q, 16 krows in regs) ---
        float p[16];
        float tm = -1e30f;
        #pragma unroll
        for (int r = 0; r < 16; ++r) {
            const int krow = (r & 3) + 8 * (r >> 2) + 4 * hi;
            const float bias = bf2f(Rl[wid][krow - q + 31][q]);
            const float s = sa[r] + bias;
            p[r] = s;
            tm = fmaxf(tm, s);
        }
        tm = fmaxf(tm, __shfl_xor(tm, 32));
        const float mn = fmaxf(m, tm);
        const float scf = __expf(m - mn);
        float ls = 0.f;
        #pragma unroll
        for (int r = 0; r < 16; ++r) { p[r] = __expf(p[r] - mn); ls += p[r]; }
        ls += __shfl_xor(ls, 32);
        l = l * scf + ls;
        m = mn;
        scb[wid][q] = scf;

        // --- pack P to bf16: Pl[q][krow] ---
        #pragma unroll
        for (int g = 0; g < 4; ++g) {
            ushort4 pk;
            pk.x = f2bf(p[4*g + 0]); pk.y = f2bf(p[4*g + 1]);
            pk.z = f2bf(p[4*g + 2]); pk.w = f2bf(p[4*g + 3]);
            *(ushort4*)&Pl[wid][q][8*g + 4*hi] = pk;
        }

        // --- PV: O[q'][d] (16x16x32, K=32) for two 16-row halves ---
        const s16x8 vf = *(const s16x8*)&Vt[lane & 15][8 * (lane >> 4)];
        {
            const s16x8 pa = *(const s16x8*)&Pl[wid][lane & 15][8 * (lane >> 4)];
            #pragma unroll
            for (int r = 0; r < 4; ++r) o0[r] *= scb[wid][(lane >> 4) * 4 + r];
            o0 = __builtin_amdgcn_mfma_f32_16x16x32_bf16(pa, vf, o0, 0, 0, 0);
        }
        {
            const s16x8 pa = *(const s16x8*)&Pl[wid][16 + (lane & 15)][8 * (lane >> 4)];
            #pragma unroll
            for (int r = 0; r < 4; ++r) o1[r] *= scb[wid][16 + (lane >> 4) * 4 + r];
            o1 = __builtin_amdgcn_mfma_f32_16x16x32_bf16(pa, vf, o1, 0, 0, 0);
        }
    }

    lb[wid][q] = l;
    const int b = bh >> 3;
    #pragma unroll
    for (int half = 0; half < 2; ++half) {
        #pragma unroll
        for (int r = 0; r < 4; ++r) {
            const int qp = half * 16 + (lane >> 4) * 4 + r;
            const float li = lb[wid][qp];
            const float val = (half ? o1[r] : o0[r]) / li;
            const int grow = b * SLEN + q0w + qp;
            Oh2[(size_t)grow * 128 + h * HD + (lane & 15)] = val;
        }
    }
}

// ================= output projection (bf16 MFMA GEMM, f32 out) =================
__global__ __launch_bounds__(256) void out_proj_mfma(
    const float* __restrict__ x, const float* __restrict__ W, const float* __restrict__ bb,
    float* __restrict__ out)
{
    __shared__ __align__(16) ushort Xs[64][40];
    __shared__ __align__(16) ushort Ws[128][40];

    const int t = threadIdx.x;
    const int wid = t >> 6, lane = t & 63;
    const int m0 = blockIdx.x * 64;

    f32x4 acc[4][2];
    #pragma unroll
    for (int i = 0; i < 4; ++i)
        #pragma unroll
        for (int j = 0; j < 2; ++j)
            #pragma unroll
            for (int r = 0; r < 4; ++r) acc[i][j][r] = 0.f;

    for (int k0 = 0; k0 < 128; k0 += 32) {
        __syncthreads();
        {
            int m = t >> 2, kb = (t & 3) * 8;
            const float* src = &x[(size_t)(m0 + m) * 128 + k0 + kb];
            const float4 a = *(const float4*)src;
            const float4 b4 = *(const float4*)(src + 4);
            ushort tmp[8] = {f2bf(a.x),f2bf(a.y),f2bf(a.z),f2bf(a.w),
                             f2bf(b4.x),f2bf(b4.y),f2bf(b4.z),f2bf(b4.w)};
            *(s16x8*)&Xs[m][kb] = *(const s16x8*)tmp;
        }
        {
            int n = t >> 1, kb = (t & 1) * 16;
            const float* src = &W[(size_t)n * 128 + k0 + kb];
            ushort tmp[16];
            #pragma unroll
            for (int i = 0; i < 16; ++i) tmp[i] = f2bf(src[i]);
            *(s16x8*)&Ws[n][kb]     = *(const s16x8*)&tmp[0];
            *(s16x8*)&Ws[n][kb + 8] = *(const s16x8*)&tmp[8];
        }
        __syncthreads();
        s16x8 af[4], bf[2];
        #pragma unroll
        for (int ms = 0; ms < 4; ++ms)
            af[ms] = *(const s16x8*)&Xs[16*ms + (lane & 15)][8 * (lane >> 4)];
        #pragma unroll
        for (int ns = 0; ns < 2; ++ns)
            bf[ns] = *(const s16x8*)&Ws[32*wid + 16*ns + (lane & 15)][8 * (lane >> 4)];
        #pragma unroll
        for (int ms = 0; ms < 4; ++ms)
            #pragma unroll
            for (int ns = 0; ns < 2; ++ns)
                acc[ms][ns] = __builtin_amdgcn_mfma_f32_16x16x32_bf16(af[ms], bf[ns], acc[ms][ns], 0, 0, 0);
    }

    #pragma unroll
    for (int ns = 0; ns < 2; ++ns) {
        const int n = 32*wid + 16*ns + (lane & 15);
        const float bias = bb[n];
        #pragma unroll
        for (int ms = 0; ms < 4; ++ms)
            #pragma unroll
            for (int r = 0; r < 4; ++r) {
                const int mm = m0 + 16*ms + (lane >> 4) * 4 + r;
                out[(size_t)mm * 128 + n] = acc[ms][ns][r] + bias;
            }
    }
}

extern "C" void kernel_launch(void* const* d_in, const int* in_sizes, int n_in,
                              void* d_out, int out_size, void* d_ws, size_t ws_size,
                              hipStream_t stream)
{
    const float* query  = (const float*)d_in[0];
    const float* key_in = (const float*)d_in[1];
    const float* value  = (const float*)d_in[2];
    const float* Wq = (const float*)d_in[3];
    const float* bq = (const float*)d_in[4];
    const float* Wk = (const float*)d_in[5];
    const float* bk = (const float*)d_in[6];
    const float* Wv = (const float*)d_in[7];
    const float* bv = (const float*)d_in[8];
    const float* Wo = (const float*)d_in[9];
    const float* bo = (const float*)d_in[10];
    const float* emb = (const float*)d_in[11];
    float* out = (float*)d_out;

    const size_t TEN = (size_t)BATCH * NH * SLEN * HD;  // 524288
    ushort* qh  = (ushort*)d_ws;
    ushort* kh  = qh + TEN;
    ushort* vtg = kh + TEN;
    float*  oh2 = (float*)(vtg + TEN);

    qkv_proj_mfma<<<dim3(64, 3), 256, 0, stream>>>(
        query, key_in, value, Wq, bq, Wk, bk, Wv, bv, qh, kh, vtg);
    attn_mfma<<<dim3(8, 32), 256, 0, stream>>>(qh, kh, vtg, emb, oh2);
    out_proj_mfma<<<dim3(64), 256, 0, stream>>>(oh2, Wo, bo, out);
}

// Round 8
// 123.303 us; speedup vs baseline: 1.5289x; 1.2595x over previous
//
#include <hip/hip_runtime.h>

#define NH 8
#define HD 16
#define SLEN 1024
#define BATCH 4
#define MAXL 500
#define NSEG 4
#define KTILES_PER_SEG 8

typedef float f32x4  __attribute__((ext_vector_type(4)));
typedef float f32x16 __attribute__((ext_vector_type(16)));
typedef short s16x8  __attribute__((ext_vector_type(8)));

__device__ inline ushort f2bf(float f) {
    uint u = __builtin_bit_cast(uint, f);
    u = (u + 0x7fffu + ((u >> 16) & 1u)) >> 16;
    return (ushort)u;
}
__device__ inline float bf2f(ushort h) {
    uint u = ((uint)h) << 16;
    return __builtin_bit_cast(float, u);
}

// ================= emb table -> bf16 (one-time) =================
__global__ __launch_bounds__(256) void emb2bf(const float* __restrict__ emb,
                                              ushort* __restrict__ emb_bf)
{
    int idx = blockIdx.x * 256 + threadIdx.x;
    int e0 = idx * 8;
    if (e0 >= (2 * MAXL + 1) * 128) return;
    const float4 a = *(const float4*)&emb[e0];
    const float4 b = *(const float4*)&emb[e0 + 4];
    ushort tmp[8] = {f2bf(a.x), f2bf(a.y), f2bf(a.z), f2bf(a.w),
                     f2bf(b.x), f2bf(b.y), f2bf(b.z), f2bf(b.w)};
    *(s16x8*)&emb_bf[e0] = *(const s16x8*)tmp;
}

// ================= QKV projection (bf16 MFMA GEMM) =================
__global__ __launch_bounds__(256) void qkv_proj_mfma(
    const float* __restrict__ xq, const float* __restrict__ xk, const float* __restrict__ xv,
    const float* __restrict__ Wq, const float* __restrict__ bq,
    const float* __restrict__ Wk, const float* __restrict__ bk,
    const float* __restrict__ Wv, const float* __restrict__ bv,
    ushort* __restrict__ Qh, ushort* __restrict__ Kh, ushort* __restrict__ Vt)
{
    const int mode = blockIdx.y;
    const float* x  = (mode == 0) ? xq : (mode == 1) ? xk : xv;
    const float* W  = (mode == 0) ? Wq : (mode == 1) ? Wk : Wv;
    const float* bb = (mode == 0) ? bq : (mode == 1) ? bk : bv;

    __shared__ __align__(16) ushort Xs[64][40];
    __shared__ __align__(16) ushort Ws[128][40];

    const int t = threadIdx.x;
    const int wid = t >> 6, lane = t & 63;
    const int m0 = blockIdx.x * 64;

    f32x4 acc[4][2];
    #pragma unroll
    for (int i = 0; i < 4; ++i)
        #pragma unroll
        for (int j = 0; j < 2; ++j)
            #pragma unroll
            for (int r = 0; r < 4; ++r) acc[i][j][r] = 0.f;

    for (int k0 = 0; k0 < 128; k0 += 32) {
        __syncthreads();
        {   // stage X tile [64][32] -> bf16
            int m = t >> 2, kb = (t & 3) * 8;
            const float* src = &x[(size_t)(m0 + m) * 128 + k0 + kb];
            const float4 a = *(const float4*)src;
            const float4 b4 = *(const float4*)(src + 4);
            ushort tmp[8] = {f2bf(a.x),f2bf(a.y),f2bf(a.z),f2bf(a.w),
                             f2bf(b4.x),f2bf(b4.y),f2bf(b4.z),f2bf(b4.w)};
            *(s16x8*)&Xs[m][kb] = *(const s16x8*)tmp;
        }
        {   // stage W tile [128][32] -> bf16
            int n = t >> 1, kb = (t & 1) * 16;
            const float* src = &W[(size_t)n * 128 + k0 + kb];
            ushort tmp[16];
            #pragma unroll
            for (int i = 0; i < 16; ++i) tmp[i] = f2bf(src[i]);
            *(s16x8*)&Ws[n][kb]     = *(const s16x8*)&tmp[0];
            *(s16x8*)&Ws[n][kb + 8] = *(const s16x8*)&tmp[8];
        }
        __syncthreads();
        s16x8 af[4], bf[2];
        #pragma unroll
        for (int ms = 0; ms < 4; ++ms)
            af[ms] = *(const s16x8*)&Xs[16*ms + (lane & 15)][8 * (lane >> 4)];
        #pragma unroll
        for (int ns = 0; ns < 2; ++ns)
            bf[ns] = *(const s16x8*)&Ws[32*wid + 16*ns + (lane & 15)][8 * (lane >> 4)];
        #pragma unroll
        for (int ms = 0; ms < 4; ++ms)
            #pragma unroll
            for (int ns = 0; ns < 2; ++ns)
                acc[ms][ns] = __builtin_amdgcn_mfma_f32_16x16x32_bf16(af[ms], bf[ns], acc[ms][ns], 0, 0, 0);
    }

    const float scale = (mode == 1) ? 0.25f : 1.0f;
    const int b = m0 >> 10;
    #pragma unroll
    for (int ns = 0; ns < 2; ++ns) {
        const int n = 32*wid + 16*ns + (lane & 15);
        const int hh = n >> 4, d = n & 15;
        const float bias = bb[n];
        #pragma unroll
        for (int ms = 0; ms < 4; ++ms) {
            if (mode == 2) {
                ushort4 pk;
                pk.x = f2bf(acc[ms][ns][0] + bias);
                pk.y = f2bf(acc[ms][ns][1] + bias);
                pk.z = f2bf(acc[ms][ns][2] + bias);
                pk.w = f2bf(acc[ms][ns][3] + bias);
                int s0 = (m0 & 1023) + 16*ms + (lane >> 4) * 4;
                *(ushort4*)&Vt[((size_t)((b*8 + hh)*16 + d)) * SLEN + s0] = pk;
            } else {
                ushort* dst = (mode == 0) ? Qh : Kh;
                #pragma unroll
                for (int r = 0; r < 4; ++r) {
                    int mm = m0 + 16*ms + (lane >> 4) * 4 + r;
                    int s = mm & 1023;
                    float v = (acc[ms][ns][r] + bias) * scale;
                    dst[((size_t)(b*8 + hh) * SLEN + s) * HD + d] = f2bf(v);
                }
            }
        }
    }
}

// ================= fused flash attention, split-k x4 (MFMA) =================
// grid (8 qgroups, 32 bh, 4 kseg); 256 thr = 4 waves; wave = 32 q rows.
__global__ __launch_bounds__(256) void attn_mfma(
    const ushort* __restrict__ Qh, const ushort* __restrict__ Kh,
    const ushort* __restrict__ Vtg, const ushort* __restrict__ emb_bf,
    float* __restrict__ mp, float* __restrict__ lp, float* __restrict__ op)
{
    __shared__ __align__(16) ushort Kt[32][24];
    __shared__ __align__(16) ushort Vt[16][40];
    __shared__ __align__(16) ushort Eb[160][24];
    __shared__ __align__(16) ushort Pl[4][32][40];
    __shared__ __align__(16) ushort Rl[4][64][36];
    __shared__ float scb[4][32];

    const int tid = threadIdx.x;
    const int wid = tid >> 6, lane = tid & 63;
    const int hi = lane >> 5, q = lane & 31;
    const int bh = blockIdx.y, h = bh & 7;
    const int q0b = blockIdx.x * 128;
    const int q0w = q0b + wid * 32;
    const int seg = blockIdx.z;

    // Q fragment straight from global (once per kernel)
    const s16x8 qf = *(const s16x8*)&Qh[((size_t)bh * SLEN + q0w + q) * HD + 8 * hi];

    f32x4 o0, o1;
    #pragma unroll
    for (int r = 0; r < 4; ++r) { o0[r] = 0.f; o1[r] = 0.f; }
    float m = -1e30f, l = 0.f;

    for (int kt = seg * KTILES_PER_SEG; kt < (seg + 1) * KTILES_PER_SEG; ++kt) {
        const int k0 = kt * 32;
        __syncthreads();
        {   // stage K tile [32][16]
            int e = tid * 2, r = e >> 4, d0 = e & 15;
            *(ushort2*)&Kt[r][d0] = *(const ushort2*)&Kh[((size_t)bh * SLEN + k0 + r) * HD + d0];
        }
        {   // stage V^T tile [16 d][32 k]
            int d = tid >> 4, kk = (tid & 15) * 2;
            *(ushort2*)&Vt[d][kk] = *(const ushort2*)&Vtg[((size_t)(bh * 16 + d)) * SLEN + k0 + kk];
        }
        {   // stage emb band [160 rel][16 kd] — pure bf16 copies
            const int relbase = k0 - q0b - 127;
            for (int e = tid; e < 160 * 2; e += 256) {
                int r = e >> 1, c8 = (e & 1) * 8;
                int rel = relbase + r;
                rel = rel < -MAXL ? -MAXL : (rel > MAXL ? MAXL : rel);
                *(s16x8*)&Eb[r][c8] =
                    *(const s16x8*)&emb_bf[(size_t)(rel + MAXL) * 128 + h * HD + c8];
            }
        }
        __syncthreads();

        // --- QK^T (swapped): sa = S^T[krow][q] ---
        const s16x8 kf = *(const s16x8*)&Kt[q][8 * hi];
        f32x16 sa;
        #pragma unroll
        for (int i = 0; i < 16; ++i) sa[i] = 0.f;
        sa = __builtin_amdgcn_mfma_f32_32x32x16_bf16(kf, qf, sa, 0, 0, 0);

        // --- R GEMM: R[q][n] = Q[q] . emb(relbase + j0w + n), n in [0,64) ---
        const int j0w = 96 - 32 * wid;
        #pragma unroll
        for (int st = 0; st < 2; ++st) {
            const s16x8 ef = *(const s16x8*)&Eb[j0w + 32 * st + q][8 * hi];
            f32x16 ra;
            #pragma unroll
            for (int i = 0; i < 16; ++i) ra[i] = 0.f;
            ra = __builtin_amdgcn_mfma_f32_32x32x16_bf16(qf, ef, ra, 0, 0, 0);
            #pragma unroll
            for (int g = 0; g < 4; ++g) {
                ushort4 pk;
                pk.x = f2bf(ra[4*g + 0]); pk.y = f2bf(ra[4*g + 1]);
                pk.z = f2bf(ra[4*g + 2]); pk.w = f2bf(ra[4*g + 3]);
                *(ushort4*)&Rl[wid][32*st + q][8*g + 4*hi] = pk;
            }
        }

        // --- bias gather + online softmax ---
        float p[16];
        float tm = -1e30f;
        #pragma unroll
        for (int r = 0; r < 16; ++r) {
            const int krow = (r & 3) + 8 * (r >> 2) + 4 * hi;
            const float bias = bf2f(Rl[wid][krow - q + 31][q]);
            const float s = sa[r] + bias;
            p[r] = s;
            tm = fmaxf(tm, s);
        }
        tm = fmaxf(tm, __shfl_xor(tm, 32));
        const float mn = fmaxf(m, tm);
        const float scf = __expf(m - mn);
        float ls = 0.f;
        #pragma unroll
        for (int r = 0; r < 16; ++r) { p[r] = __expf(p[r] - mn); ls += p[r]; }
        ls += __shfl_xor(ls, 32);
        l = l * scf + ls;
        m = mn;
        scb[wid][q] = scf;

        // --- pack P to bf16: Pl[q][krow] ---
        #pragma unroll
        for (int g = 0; g < 4; ++g) {
            ushort4 pk;
            pk.x = f2bf(p[4*g + 0]); pk.y = f2bf(p[4*g + 1]);
            pk.z = f2bf(p[4*g + 2]); pk.w = f2bf(p[4*g + 3]);
            *(ushort4*)&Pl[wid][q][8*g + 4*hi] = pk;
        }

        // --- PV (16x16x32) for two 16-row halves ---
        const s16x8 vf = *(const s16x8*)&Vt[lane & 15][8 * (lane >> 4)];
        {
            const s16x8 pa = *(const s16x8*)&Pl[wid][lane & 15][8 * (lane >> 4)];
            #pragma unroll
            for (int r = 0; r < 4; ++r) o0[r] *= scb[wid][(lane >> 4) * 4 + r];
            o0 = __builtin_amdgcn_mfma_f32_16x16x32_bf16(pa, vf, o0, 0, 0, 0);
        }
        {
            const s16x8 pa = *(const s16x8*)&Pl[wid][16 + (lane & 15)][8 * (lane >> 4)];
            #pragma unroll
            for (int r = 0; r < 4; ++r) o1[r] *= scb[wid][16 + (lane >> 4) * 4 + r];
            o1 = __builtin_amdgcn_mfma_f32_16x16x32_bf16(pa, vf, o1, 0, 0, 0);
        }
    }

    // --- write raw partials (no normalize) ---
    const size_t pbase = (size_t)(seg * 32 + bh) * SLEN;
    if (hi == 0) {
        mp[pbase + q0w + q] = m;
        lp[pbase + q0w + q] = l;
    }
    #pragma unroll
    for (int half = 0; half < 2; ++half) {
        #pragma unroll
        for (int r = 0; r < 4; ++r) {
            const int qp = half * 16 + (lane >> 4) * 4 + r;
            op[(pbase + q0w + qp) * HD + (lane & 15)] = (half ? o1[r] : o0[r]);
        }
    }
}

// ================= split-k merge -> Oh2[b*S+q][h*16+d] =================
__global__ __launch_bounds__(256) void merge_kernel(
    const float* __restrict__ mp, const float* __restrict__ lp,
    const float* __restrict__ op, float* __restrict__ Oh2)
{
    const int idx = blockIdx.x * 256 + threadIdx.x;   // over 32*1024*16
    const int d = idx & 15;
    const int row = idx >> 4;                          // bh*1024 + q
    const int bh = row >> 10, q = row & 1023;
    const int h = bh & 7, b = bh >> 3;

    float ms[NSEG];
    float M = -1e30f;
    #pragma unroll
    for (int s = 0; s < NSEG; ++s) {
        ms[s] = mp[(size_t)s * 32 * SLEN + row];
        M = fmaxf(M, ms[s]);
    }
    float L = 0.f, acc = 0.f;
    #pragma unroll
    for (int s = 0; s < NSEG; ++s) {
        const float w = __expf(ms[s] - M);
        L += lp[(size_t)s * 32 * SLEN + row] * w;
        acc += op[((size_t)s * 32 * SLEN + row) * HD + d] * w;
    }
    Oh2[((size_t)(b * SLEN + q)) * 128 + h * HD + d] = acc / L;
}

// ================= output projection (bf16 MFMA GEMM, f32 out) =================
__global__ __launch_bounds__(256) void out_proj_mfma(
    const float* __restrict__ x, const float* __restrict__ W, const float* __restrict__ bb,
    float* __restrict__ out)
{
    __shared__ __align__(16) ushort Xs[64][40];
    __shared__ __align__(16) ushort Ws[128][40];

    const int t = threadIdx.x;
    const int wid = t >> 6, lane = t & 63;
    const int m0 = blockIdx.x * 64;

    f32x4 acc[4][2];
    #pragma unroll
    for (int i = 0; i < 4; ++i)
        #pragma unroll
        for (int j = 0; j < 2; ++j)
            #pragma unroll
            for (int r = 0; r < 4; ++r) acc[i][j][r] = 0.f;

    for (int k0 = 0; k0 < 128; k0 += 32) {
        __syncthreads();
        {
            int m = t >> 2, kb = (t & 3) * 8;
            const float* src = &x[(size_t)(m0 + m) * 128 + k0 + kb];
            const float4 a = *(const float4*)src;
            const float4 b4 = *(const float4*)(src + 4);
            ushort tmp[8] = {f2bf(a.x),f2bf(a.y),f2bf(a.z),f2bf(a.w),
                             f2bf(b4.x),f2bf(b4.y),f2bf(b4.z),f2bf(b4.w)};
            *(s16x8*)&Xs[m][kb] = *(const s16x8*)tmp;
        }
        {
            int n = t >> 1, kb = (t & 1) * 16;
            const float* src = &W[(size_t)n * 128 + k0 + kb];
            ushort tmp[16];
            #pragma unroll
            for (int i = 0; i < 16; ++i) tmp[i] = f2bf(src[i]);
            *(s16x8*)&Ws[n][kb]     = *(const s16x8*)&tmp[0];
            *(s16x8*)&Ws[n][kb + 8] = *(const s16x8*)&tmp[8];
        }
        __syncthreads();
        s16x8 af[4], bf[2];
        #pragma unroll
        for (int ms = 0; ms < 4; ++ms)
            af[ms] = *(const s16x8*)&Xs[16*ms + (lane & 15)][8 * (lane >> 4)];
        #pragma unroll
        for (int ns = 0; ns < 2; ++ns)
            bf[ns] = *(const s16x8*)&Ws[32*wid + 16*ns + (lane & 15)][8 * (lane >> 4)];
        #pragma unroll
        for (int ms = 0; ms < 4; ++ms)
            #pragma unroll
            for (int ns = 0; ns < 2; ++ns)
                acc[ms][ns] = __builtin_amdgcn_mfma_f32_16x16x32_bf16(af[ms], bf[ns], acc[ms][ns], 0, 0, 0);
    }

    #pragma unroll
    for (int ns = 0; ns < 2; ++ns) {
        const int n = 32*wid + 16*ns + (lane & 15);
        const float bias = bb[n];
        #pragma unroll
        for (int ms = 0; ms < 4; ++ms)
            #pragma unroll
            for (int r = 0; r < 4; ++r) {
                const int mm = m0 + 16*ms + (lane >> 4) * 4 + r;
                out[(size_t)mm * 128 + n] = acc[ms][ns][r] + bias;
            }
    }
}

extern "C" void kernel_launch(void* const* d_in, const int* in_sizes, int n_in,
                              void* d_out, int out_size, void* d_ws, size_t ws_size,
                              hipStream_t stream)
{
    const float* query  = (const float*)d_in[0];
    const float* key_in = (const float*)d_in[1];
    const float* value  = (const float*)d_in[2];
    const float* Wq = (const float*)d_in[3];
    const float* bq = (const float*)d_in[4];
    const float* Wk = (const float*)d_in[5];
    const float* bk = (const float*)d_in[6];
    const float* Wv = (const float*)d_in[7];
    const float* bv = (const float*)d_in[8];
    const float* Wo = (const float*)d_in[9];
    const float* bo = (const float*)d_in[10];
    const float* emb = (const float*)d_in[11];
    float* out = (float*)d_out;

    const size_t TEN = (size_t)BATCH * NH * SLEN * HD;      // 524288
    const size_t ROWS = (size_t)32 * SLEN;                  // 32768 rows (bh*q)
    ushort* qh  = (ushort*)d_ws;
    ushort* kh  = qh + TEN;
    ushort* vtg = kh + TEN;
    float*  oh2 = (float*)(vtg + TEN);                      // 4096*128 f32
    float*  mp  = oh2 + (size_t)4096 * 128;                 // NSEG*ROWS
    float*  lp  = mp + NSEG * ROWS;
    float*  op  = lp + NSEG * ROWS;                         // NSEG*ROWS*16
    ushort* embbf = (ushort*)(op + NSEG * ROWS * HD);       // 1001*128

    emb2bf<<<63, 256, 0, stream>>>(emb, embbf);
    qkv_proj_mfma<<<dim3(64, 3), 256, 0, stream>>>(
        query, key_in, value, Wq, bq, Wk, bk, Wv, bv, qh, kh, vtg);
    attn_mfma<<<dim3(8, 32, NSEG), 256, 0, stream>>>(qh, kh, vtg, embbf, mp, lp, op);
    merge_kernel<<<(32 * SLEN * HD) / 256, 256, 0, stream>>>(mp, lp, op, oh2);
    out_proj_mfma<<<64, 256, 0, stream>>>(oh2, Wo, bo, out);
}

// Round 9
// 120.185 us; speedup vs baseline: 1.5686x; 1.0259x over previous
//
#include <hip/hip_runtime.h>

#define NH 8
#define HD 16
#define SLEN 1024
#define BATCH 4
#define MAXL 500
#define NSEG 4
#define KTILES_PER_SEG 8

typedef float f32x4  __attribute__((ext_vector_type(4)));
typedef float f32x16 __attribute__((ext_vector_type(16)));
typedef short s16x8  __attribute__((ext_vector_type(8)));

__device__ inline ushort f2bf(float f) {
    uint u = __builtin_bit_cast(uint, f);
    u = (u + 0x7fffu + ((u >> 16) & 1u)) >> 16;
    return (ushort)u;
}
__device__ inline float bf2f(ushort h) {
    uint u = ((uint)h) << 16;
    return __builtin_bit_cast(float, u);
}

// ============ K1: one-shot f32 -> bf16 conversion of all GEMM operands ============
// regions: 3 x inputs (3*524288), 4 weights (4*16384), emb (128128)
__global__ __launch_bounds__(256) void prep_bf16(
    const float* __restrict__ xq, const float* __restrict__ xk, const float* __restrict__ xv,
    const float* __restrict__ Wq, const float* __restrict__ Wk,
    const float* __restrict__ Wv, const float* __restrict__ Wo,
    const float* __restrict__ emb,
    ushort* __restrict__ xqb, ushort* __restrict__ xkb, ushort* __restrict__ xvb,
    ushort* __restrict__ wqb, ushort* __restrict__ wkb,
    ushort* __restrict__ wvb, ushort* __restrict__ wob,
    ushort* __restrict__ embb)
{
    const int XTOT = 3 * 524288;
    const int WTOT = 4 * 16384;
    const int ETOT = (2 * MAXL + 1) * 128;   // 128128
    int e0 = (blockIdx.x * 256 + threadIdx.x) * 8;
    const float* src;
    ushort* dst;
    int off;
    if (e0 < XTOT) {
        int which = e0 >> 19; off = e0 & 524287;
        src = which == 0 ? xq : which == 1 ? xk : xv;
        dst = which == 0 ? xqb : which == 1 ? xkb : xvb;
    } else if (e0 < XTOT + WTOT) {
        int t = e0 - XTOT; int which = t >> 14; off = t & 16383;
        src = which == 0 ? Wq : which == 1 ? Wk : which == 2 ? Wv : Wo;
        dst = which == 0 ? wqb : which == 1 ? wkb : which == 2 ? wvb : wob;
    } else if (e0 < XTOT + WTOT + ETOT) {
        off = e0 - XTOT - WTOT; src = emb; dst = embb;
    } else {
        return;
    }
    const float4 a = *(const float4*)&src[off];
    const float4 b = *(const float4*)&src[off + 4];
    ushort tmp[8] = {f2bf(a.x), f2bf(a.y), f2bf(a.z), f2bf(a.w),
                     f2bf(b.x), f2bf(b.y), f2bf(b.z), f2bf(b.w)};
    *(s16x8*)&dst[off] = *(const s16x8*)tmp;
}

// ============ K2: QKV projection — LDS-free 1-wave MFMA GEMM ============
// grid (512, 3): blockIdx.x = mt*4+nq (32-row x 32-col tile), y = mode.
__global__ __launch_bounds__(64) void qkv_gemm(
    const ushort* __restrict__ xqb, const ushort* __restrict__ xkb, const ushort* __restrict__ xvb,
    const ushort* __restrict__ wqb, const ushort* __restrict__ wkb, const ushort* __restrict__ wvb,
    const float* __restrict__ bq, const float* __restrict__ bk, const float* __restrict__ bv,
    ushort* __restrict__ Qh, ushort* __restrict__ Kh, ushort* __restrict__ Vt)
{
    const int mode = blockIdx.y;
    const ushort* X = mode == 0 ? xqb : mode == 1 ? xkb : xvb;
    const ushort* W = mode == 0 ? wqb : mode == 1 ? wkb : wvb;
    const float* bb = mode == 0 ? bq : mode == 1 ? bk : bv;

    const int l = threadIdx.x;
    const int row = l & 15, kh = l >> 4;        // A/B fragment row, k-half
    const int mt = blockIdx.x >> 2, nq = blockIdx.x & 3;
    const int m0 = mt * 32, n0 = nq * 32;

    s16x8 af[2][4], bfr[2][4];
    #pragma unroll
    for (int ms = 0; ms < 2; ++ms)
        #pragma unroll
        for (int ki = 0; ki < 4; ++ki)
            af[ms][ki] = *(const s16x8*)&X[(size_t)(m0 + 16*ms + row) * 128 + 32*ki + 8*kh];
    #pragma unroll
    for (int ns = 0; ns < 2; ++ns)
        #pragma unroll
        for (int ki = 0; ki < 4; ++ki)
            bfr[ns][ki] = *(const s16x8*)&W[(size_t)(n0 + 16*ns + row) * 128 + 32*ki + 8*kh];

    f32x4 acc[2][2];
    #pragma unroll
    for (int ms = 0; ms < 2; ++ms)
        #pragma unroll
        for (int ns = 0; ns < 2; ++ns)
            #pragma unroll
            for (int r = 0; r < 4; ++r) acc[ms][ns][r] = 0.f;

    #pragma unroll
    for (int ki = 0; ki < 4; ++ki)
        #pragma unroll
        for (int ms = 0; ms < 2; ++ms)
            #pragma unroll
            for (int ns = 0; ns < 2; ++ns)
                acc[ms][ns] = __builtin_amdgcn_mfma_f32_16x16x32_bf16(af[ms][ki], bfr[ns][ki], acc[ms][ns], 0, 0, 0);

    const float scale = (mode == 1) ? 0.25f : 1.0f;
    const int b = m0 >> 10;
    #pragma unroll
    for (int ns = 0; ns < 2; ++ns) {
        const int n = n0 + 16*ns + row;          // C col = lane&15 (+offsets)
        const int hh = n >> 4, d = n & 15;
        const float bias = bb[n];
        #pragma unroll
        for (int ms = 0; ms < 2; ++ms) {
            if (mode == 2) {
                ushort4 pk;
                pk.x = f2bf(acc[ms][ns][0] + bias);
                pk.y = f2bf(acc[ms][ns][1] + bias);
                pk.z = f2bf(acc[ms][ns][2] + bias);
                pk.w = f2bf(acc[ms][ns][3] + bias);
                const int s0 = (m0 & 1023) + 16*ms + kh * 4;
                *(ushort4*)&Vt[((size_t)((b*8 + hh)*16 + d)) * SLEN + s0] = pk;
            } else {
                ushort* dst = (mode == 0) ? Qh : Kh;
                #pragma unroll
                for (int r = 0; r < 4; ++r) {
                    const int mm = m0 + 16*ms + kh * 4 + r;
                    const int s = mm & 1023;
                    dst[((size_t)(b*8 + hh) * SLEN + s) * HD + d] = f2bf((acc[ms][ns][r] + bias) * scale);
                }
            }
        }
    }
}

// ============ K3: fused flash attention, split-k x4 (unchanged from round 8) ============
__global__ __launch_bounds__(256) void attn_mfma(
    const ushort* __restrict__ Qh, const ushort* __restrict__ Kh,
    const ushort* __restrict__ Vtg, const ushort* __restrict__ emb_bf,
    float* __restrict__ mp, float* __restrict__ lp, float* __restrict__ op)
{
    __shared__ __align__(16) ushort Kt[32][24];
    __shared__ __align__(16) ushort Vt[16][40];
    __shared__ __align__(16) ushort Eb[160][24];
    __shared__ __align__(16) ushort Pl[4][32][40];
    __shared__ __align__(16) ushort Rl[4][64][36];
    __shared__ float scb[4][32];

    const int tid = threadIdx.x;
    const int wid = tid >> 6, lane = tid & 63;
    const int hi = lane >> 5, q = lane & 31;
    const int bh = blockIdx.y, h = bh & 7;
    const int q0b = blockIdx.x * 128;
    const int q0w = q0b + wid * 32;
    const int seg = blockIdx.z;

    const s16x8 qf = *(const s16x8*)&Qh[((size_t)bh * SLEN + q0w + q) * HD + 8 * hi];

    f32x4 o0, o1;
    #pragma unroll
    for (int r = 0; r < 4; ++r) { o0[r] = 0.f; o1[r] = 0.f; }
    float m = -1e30f, l = 0.f;

    for (int kt = seg * KTILES_PER_SEG; kt < (seg + 1) * KTILES_PER_SEG; ++kt) {
        const int k0 = kt * 32;
        __syncthreads();
        {
            int e = tid * 2, r = e >> 4, d0 = e & 15;
            *(ushort2*)&Kt[r][d0] = *(const ushort2*)&Kh[((size_t)bh * SLEN + k0 + r) * HD + d0];
        }
        {
            int d = tid >> 4, kk = (tid & 15) * 2;
            *(ushort2*)&Vt[d][kk] = *(const ushort2*)&Vtg[((size_t)(bh * 16 + d)) * SLEN + k0 + kk];
        }
        {
            const int relbase = k0 - q0b - 127;
            for (int e = tid; e < 160 * 2; e += 256) {
                int r = e >> 1, c8 = (e & 1) * 8;
                int rel = relbase + r;
                rel = rel < -MAXL ? -MAXL : (rel > MAXL ? MAXL : rel);
                *(s16x8*)&Eb[r][c8] =
                    *(const s16x8*)&emb_bf[(size_t)(rel + MAXL) * 128 + h * HD + c8];
            }
        }
        __syncthreads();

        const s16x8 kf = *(const s16x8*)&Kt[q][8 * hi];
        f32x16 sa;
        #pragma unroll
        for (int i = 0; i < 16; ++i) sa[i] = 0.f;
        sa = __builtin_amdgcn_mfma_f32_32x32x16_bf16(kf, qf, sa, 0, 0, 0);

        const int j0w = 96 - 32 * wid;
        #pragma unroll
        for (int st = 0; st < 2; ++st) {
            const s16x8 ef = *(const s16x8*)&Eb[j0w + 32 * st + q][8 * hi];
            f32x16 ra;
            #pragma unroll
            for (int i = 0; i < 16; ++i) ra[i] = 0.f;
            ra = __builtin_amdgcn_mfma_f32_32x32x16_bf16(qf, ef, ra, 0, 0, 0);
            #pragma unroll
            for (int g = 0; g < 4; ++g) {
                ushort4 pk;
                pk.x = f2bf(ra[4*g + 0]); pk.y = f2bf(ra[4*g + 1]);
                pk.z = f2bf(ra[4*g + 2]); pk.w = f2bf(ra[4*g + 3]);
                *(ushort4*)&Rl[wid][32*st + q][8*g + 4*hi] = pk;
            }
        }

        float p[16];
        float tm = -1e30f;
        #pragma unroll
        for (int r = 0; r < 16; ++r) {
            const int krow = (r & 3) + 8 * (r >> 2) + 4 * hi;
            const float bias = bf2f(Rl[wid][krow - q + 31][q]);
            const float s = sa[r] + bias;
            p[r] = s;
            tm = fmaxf(tm, s);
        }
        tm = fmaxf(tm, __shfl_xor(tm, 32));
        const float mn = fmaxf(m, tm);
        const float scf = __expf(m - mn);
        float ls = 0.f;
        #pragma unroll
        for (int r = 0; r < 16; ++r) { p[r] = __expf(p[r] - mn); ls += p[r]; }
        ls += __shfl_xor(ls, 32);
        l = l * scf + ls;
        m = mn;
        scb[wid][q] = scf;

        #pragma unroll
        for (int g = 0; g < 4; ++g) {
            ushort4 pk;
            pk.x = f2bf(p[4*g + 0]); pk.y = f2bf(p[4*g + 1]);
            pk.z = f2bf(p[4*g + 2]); pk.w = f2bf(p[4*g + 3]);
            *(ushort4*)&Pl[wid][q][8*g + 4*hi] = pk;
        }

        const s16x8 vf = *(const s16x8*)&Vt[lane & 15][8 * (lane >> 4)];
        {
            const s16x8 pa = *(const s16x8*)&Pl[wid][lane & 15][8 * (lane >> 4)];
            #pragma unroll
            for (int r = 0; r < 4; ++r) o0[r] *= scb[wid][(lane >> 4) * 4 + r];
            o0 = __builtin_amdgcn_mfma_f32_16x16x32_bf16(pa, vf, o0, 0, 0, 0);
        }
        {
            const s16x8 pa = *(const s16x8*)&Pl[wid][16 + (lane & 15)][8 * (lane >> 4)];
            #pragma unroll
            for (int r = 0; r < 4; ++r) o1[r] *= scb[wid][16 + (lane >> 4) * 4 + r];
            o1 = __builtin_amdgcn_mfma_f32_16x16x32_bf16(pa, vf, o1, 0, 0, 0);
        }
    }

    const size_t pbase = (size_t)(seg * 32 + bh) * SLEN;
    if (hi == 0) {
        mp[pbase + q0w + q] = m;
        lp[pbase + q0w + q] = l;
    }
    #pragma unroll
    for (int half = 0; half < 2; ++half) {
        #pragma unroll
        for (int r = 0; r < 4; ++r) {
            const int qp = half * 16 + (lane >> 4) * 4 + r;
            op[(pbase + q0w + qp) * HD + (lane & 15)] = (half ? o1[r] : o0[r]);
        }
    }
}

// ============ K4: split-k merge -> bf16 ohbf[b*S+q][h*16+d] ============
__global__ __launch_bounds__(256) void merge_kernel(
    const float* __restrict__ mp, const float* __restrict__ lp,
    const float* __restrict__ op, ushort* __restrict__ ohbf)
{
    const int idx = blockIdx.x * 256 + threadIdx.x;
    const int d = idx & 15;
    const int row = idx >> 4;                          // bh*1024 + q
    const int bh = row >> 10, q = row & 1023;
    const int h = bh & 7, b = bh >> 3;

    float ms[NSEG];
    float M = -1e30f;
    #pragma unroll
    for (int s = 0; s < NSEG; ++s) {
        ms[s] = mp[(size_t)s * 32 * SLEN + row];
        M = fmaxf(M, ms[s]);
    }
    float L = 0.f, acc = 0.f;
    #pragma unroll
    for (int s = 0; s < NSEG; ++s) {
        const float w = __expf(ms[s] - M);
        L += lp[(size_t)s * 32 * SLEN + row] * w;
        acc += op[((size_t)s * 32 * SLEN + row) * HD + d] * w;
    }
    ohbf[((size_t)(b * SLEN + q)) * 128 + h * HD + d] = f2bf(acc / L);
}

// ============ K5: output projection — LDS-free 1-wave MFMA GEMM, f32 out ============
__global__ __launch_bounds__(64) void out_gemm(
    const ushort* __restrict__ ohbf, const ushort* __restrict__ wob,
    const float* __restrict__ bo, float* __restrict__ out)
{
    const int l = threadIdx.x;
    const int row = l & 15, kh = l >> 4;
    const int mt = blockIdx.x >> 2, nq = blockIdx.x & 3;
    const int m0 = mt * 32, n0 = nq * 32;

    s16x8 af[2][4], bfr[2][4];
    #pragma unroll
    for (int ms = 0; ms < 2; ++ms)
        #pragma unroll
        for (int ki = 0; ki < 4; ++ki)
            af[ms][ki] = *(const s16x8*)&ohbf[(size_t)(m0 + 16*ms + row) * 128 + 32*ki + 8*kh];
    #pragma unroll
    for (int ns = 0; ns < 2; ++ns)
        #pragma unroll
        for (int ki = 0; ki < 4; ++ki)
            bfr[ns][ki] = *(const s16x8*)&wob[(size_t)(n0 + 16*ns + row) * 128 + 32*ki + 8*kh];

    f32x4 acc[2][2];
    #pragma unroll
    for (int ms = 0; ms < 2; ++ms)
        #pragma unroll
        for (int ns = 0; ns < 2; ++ns)
            #pragma unroll
            for (int r = 0; r < 4; ++r) acc[ms][ns][r] = 0.f;

    #pragma unroll
    for (int ki = 0; ki < 4; ++ki)
        #pragma unroll
        for (int ms = 0; ms < 2; ++ms)
            #pragma unroll
            for (int ns = 0; ns < 2; ++ns)
                acc[ms][ns] = __builtin_amdgcn_mfma_f32_16x16x32_bf16(af[ms][ki], bfr[ns][ki], acc[ms][ns], 0, 0, 0);

    #pragma unroll
    for (int ns = 0; ns < 2; ++ns) {
        const int n = n0 + 16*ns + row;
        const float bias = bo[n];
        #pragma unroll
        for (int ms = 0; ms < 2; ++ms)
            #pragma unroll
            for (int r = 0; r < 4; ++r) {
                const int mm = m0 + 16*ms + kh * 4 + r;
                out[(size_t)mm * 128 + n] = acc[ms][ns][r] + bias;
            }
    }
}

extern "C" void kernel_launch(void* const* d_in, const int* in_sizes, int n_in,
                              void* d_out, int out_size, void* d_ws, size_t ws_size,
                              hipStream_t stream)
{
    const float* query  = (const float*)d_in[0];
    const float* key_in = (const float*)d_in[1];
    const float* value  = (const float*)d_in[2];
    const float* Wq = (const float*)d_in[3];
    const float* bq = (const float*)d_in[4];
    const float* Wk = (const float*)d_in[5];
    const float* bk = (const float*)d_in[6];
    const float* Wv = (const float*)d_in[7];
    const float* bv = (const float*)d_in[8];
    const float* Wo = (const float*)d_in[9];
    const float* bo = (const float*)d_in[10];
    const float* emb = (const float*)d_in[11];
    float* out = (float*)d_out;

    const size_t TEN = (size_t)BATCH * NH * SLEN * HD;      // 524288
    const size_t WE  = 16384;
    const size_t EE  = (size_t)(2 * MAXL + 1) * 128;        // 128128
    const size_t ROWS = (size_t)32 * SLEN;                  // 32768

    ushort* qh   = (ushort*)d_ws;
    ushort* kh   = qh + TEN;
    ushort* vtg  = kh + TEN;
    ushort* xqb  = vtg + TEN;
    ushort* xkb  = xqb + TEN;
    ushort* xvb  = xkb + TEN;
    ushort* wqb  = xvb + TEN;
    ushort* wkb  = wqb + WE;
    ushort* wvb  = wkb + WE;
    ushort* wob  = wvb + WE;
    ushort* embb = wob + WE;
    ushort* ohbf = embb + EE;
    float*  mp   = (float*)(ohbf + TEN);
    float*  lp   = mp + NSEG * ROWS;
    float*  op   = lp + NSEG * ROWS;                        // NSEG*ROWS*16 f32

    prep_bf16<<<863, 256, 0, stream>>>(query, key_in, value, Wq, Wk, Wv, Wo, emb,
                                       xqb, xkb, xvb, wqb, wkb, wvb, wob, embb);
    qkv_gemm<<<dim3(512, 3), 64, 0, stream>>>(xqb, xkb, xvb, wqb, wkb, wvb,
                                              bq, bk, bv, qh, kh, vtg);
    attn_mfma<<<dim3(8, 32, NSEG), 256, 0, stream>>>(qh, kh, vtg, embb, mp, lp, op);
    merge_kernel<<<(32 * SLEN * HD) / 256, 256, 0, stream>>>(mp, lp, op, ohbf);
    out_gemm<<<512, 64, 0, stream>>>(ohbf, wob, bo, out);
}